// Round 2
// 1150.410 us; speedup vs baseline: 1.5365x; 1.5365x over previous
//
#include <hip/hip_runtime.h>
#include <cstdint>
#include <cstddef>

#define BATCH_N 32768
#define IND 768
#define HID 2048

typedef __attribute__((ext_vector_type(4))) float float4v;
typedef __attribute__((ext_vector_type(4))) _Float16 half4v;
typedef __attribute__((ext_vector_type(8))) _Float16 half8v;

// ---------------- prep: W_enc -> fp16, scaled by 1024 ------------------------
__global__ __launch_bounds__(256) void prep_wenc(const float* __restrict__ W,
                                                 _Float16* __restrict__ Whi)
{
    const int t = blockIdx.x * 256 + threadIdx.x;   // 0 .. 2048*768/4-1
    float4v f = ((const float4v*)W)[t];
    half4v hv = {(_Float16)(f.x * 1024.0f), (_Float16)(f.y * 1024.0f),
                 (_Float16)(f.z * 1024.0f), (_Float16)(f.w * 1024.0f)};
    ((half4v*)Whi)[t] = hv;
}

// ---------------- prep: W_dec [768][2048] -> W_decT [2048][768] fp32 ---------
__global__ __launch_bounds__(256) void prep_wdec(const float* __restrict__ Wd,
                                                 float* __restrict__ WdT)
{
    const int t = blockIdx.x * 256 + threadIdx.x;   // over 2048*768 outputs
    const int h = t / IND;
    const int d = t - h * IND;
    WdT[t] = Wd[(size_t)d * HID + h];
}

// ---------------- encoder GEMM (approx): h~ = x @ W_enc^T + b_enc ------------
// single fp16 MFMA, W pre-scaled by 1024, epilogue rescales by 2^-10.
// 128x128 tile, BK=32, 4 waves. Error ~1.4e-4 RMS — plenty for outputs and
// for candidate screening; exact selection happens in topk_refine.
__global__ __launch_bounds__(256) void gemm_enc(
    const float* __restrict__ x, const _Float16* __restrict__ Whi,
    const float* __restrict__ benc, float* __restrict__ hpre)
{
    __shared__ __align__(16) _Float16 sAh[128 * 32];
    __shared__ __align__(16) _Float16 sBh[128 * 32];

    const int tid  = threadIdx.x;
    const int lane = tid & 63;
    const int wave = tid >> 6;
    const int mt = blockIdx.x >> 4;     // 256 m-tiles
    const int nt = blockIdx.x & 15;     // 16 n-tiles
    const int M0 = mt << 7, N0 = nt << 7;

    // staging map: 2 threads per tile-row, 16 elements each
    const int srow  = tid >> 1;
    const int shalf = (tid & 1) << 4;   // 0 or 16 (elements)
    const float*    xg  = x   + (size_t)(M0 + srow) * IND + shalf;
    const _Float16* bhg = Whi + (size_t)(N0 + srow) * IND + shalf;
    _Float16* sah = sAh + srow * 32 + shalf;
    _Float16* sbh = sBh + srow * 32 + shalf;

    const int wm  = (wave & 1) << 6;
    const int wn  = (wave >> 1) << 6;
    const int fr  = lane & 15;
    const int fko = (lane >> 4) << 3;

    float4v acc[4][4] = {};

#pragma unroll 1
    for (int kt = 0; kt < 24; ++kt) {
        const int k0 = kt << 5;
        float4v f0 = *(const float4v*)(xg + k0);
        float4v f1 = *(const float4v*)(xg + k0 + 4);
        float4v f2 = *(const float4v*)(xg + k0 + 8);
        float4v f3 = *(const float4v*)(xg + k0 + 12);
        half8v wh0 = *(const half8v*)(bhg + k0);
        half8v wh1 = *(const half8v*)(bhg + k0 + 8);

        __syncthreads();   // previous iteration's LDS reads done

        half8v ha0 = {(_Float16)f0.x, (_Float16)f0.y, (_Float16)f0.z, (_Float16)f0.w,
                      (_Float16)f1.x, (_Float16)f1.y, (_Float16)f1.z, (_Float16)f1.w};
        half8v ha1 = {(_Float16)f2.x, (_Float16)f2.y, (_Float16)f2.z, (_Float16)f2.w,
                      (_Float16)f3.x, (_Float16)f3.y, (_Float16)f3.z, (_Float16)f3.w};
        *(half8v*)(sah)     = ha0;
        *(half8v*)(sah + 8) = ha1;
        *(half8v*)(sbh)     = wh0;
        *(half8v*)(sbh + 8) = wh1;

        __syncthreads();

        half8v Ah[4], Bh[4];
#pragma unroll
        for (int i = 0; i < 4; ++i) {
            Ah[i] = *(const half8v*)&sAh[(wm + i*16 + fr)*32 + fko];
            Bh[i] = *(const half8v*)&sBh[(wn + i*16 + fr)*32 + fko];
        }
#pragma unroll
        for (int i = 0; i < 4; ++i)
#pragma unroll
            for (int j = 0; j < 4; ++j)
                acc[i][j] = __builtin_amdgcn_mfma_f32_16x16x32_f16(Ah[i], Bh[j], acc[i][j], 0, 0, 0);
    }

    // epilogue: rescale by 2^-10, add bias, store.
    // C/D mapping (m89/m91-verified): col = lane&15, row = (lane>>4)*4 + reg
    const float inv = 1.0f / 1024.0f;
#pragma unroll
    for (int j = 0; j < 4; ++j) {
        const int col = N0 + wn + j*16 + fr;
        const float bias = benc[col];
#pragma unroll
        for (int i = 0; i < 4; ++i) {
            const int row0 = M0 + wm + i*16 + ((lane >> 4) << 2);
            float* p = hpre + (size_t)row0 * HID + col;
            p[0]       = acc[i][j][0] * inv + bias;
            p[HID]     = acc[i][j][1] * inv + bias;
            p[2 * HID] = acc[i][j][2] * inv + bias;
            p[3 * HID] = acc[i][j][3] * inv + bias;
        }
    }
}

// -------------------- wave helpers (wave64) ----------------------------------
__device__ __forceinline__ int wsum_i(int v) {
#pragma unroll
    for (int o = 32; o; o >>= 1) v += __shfl_xor(v, o);
    return v;
}
__device__ __forceinline__ float wsum_f(float v) {
#pragma unroll
    for (int o = 32; o; o >>= 1) v += __shfl_xor(v, o);
    return v;
}
__device__ __forceinline__ int wscan_excl(int v, int lane) {
    int s = v;
#pragma unroll
    for (int o = 1; o < 64; o <<= 1) {
        int t = __shfl_up(s, o);
        if (lane >= o) s += t;
    }
    return s - v;   // exclusive prefix; inclusive = s
}

// ---------------- top-k: threshold screen + band-limited fp64 refine ---------
// One wave per row. Lane owns columns [lane*32, lane*32+32).
//
// Phases:
//  1. Row mu/sigma -> Gaussian-guided float threshold th with
//     count(v >= th) in [32,56]. Counting is 1 v_cmp + scalar bcnt per
//     element (ballot trick) -- no butterflies, no serial argmax.
//  2. Compact candidates (<=64) one-per-lane via per-wave LDS.
//  3. Bitwise radix-select over candidates -> thf = exact 32nd-largest
//     approx value (greedy max-T with count(>=T)>=32; handles duplicates).
//  4. Error band: |approx-exact| <= E (E=2e-3 ~ 14 sigma of the measured
//     1.4e-4 RMS fp16-GEMM error; bulletproof for CLT-Gaussian error sums).
//       v >  thf+2E  -> provably in top-32 ("sure")
//       v <  thf-2E  -> provably out
//       band [thf-2E, thf+2E] (typically 1-3 elems) -> exact fp64 dot,
//       take top-(32 - n_sure) by (exact desc, idx asc) == lax.top_k ties.
//     Winner SET is identical to fp64-ranking a wide screen (old kernel),
//     so outputs are value-identical. If th > thf-2E (rare ~4%), append the
//     uncovered sliver [thf-2E, th) as extra band candidates.
//  5. Scatter h_sparse (float4 stores) and compact (idx,val) for decoder.
// Degenerate mass-tie rows fall back to capped enumeration in ascending
// column order, matching lax.top_k's lowest-index tie preference.
#define TOPK_E 2.0e-3f

__global__ __launch_bounds__(256) void topk_refine(
    const float* __restrict__ hpre, const float* __restrict__ x,
    const float* __restrict__ Wenc, const float* __restrict__ benc,
    float* __restrict__ hsp, int* __restrict__ oidx, float* __restrict__ oval)
{
    __shared__ int   cidxS[4][64];
    __shared__ float cvalS[4][64];

    const int lane = threadIdx.x & 63;
    const int wave = threadIdx.x >> 6;
    const int row  = blockIdx.x * 4 + wave;

    // ---- load row (vectorized, lane-contiguous ownership)
    const float4v* hp4 = (const float4v*)(hpre + (size_t)row * HID + lane * 32);
    float v[32];
#pragma unroll
    for (int ii = 0; ii < 8; ++ii) {
        float4v f = hp4[ii];
        v[ii*4+0] = f.x; v[ii*4+1] = f.y; v[ii*4+2] = f.z; v[ii*4+3] = f.w;
    }

    // ---- phase 1a: row mean / std
    float s1 = 0.f, s2 = 0.f;
#pragma unroll
    for (int i = 0; i < 32; ++i) { s1 += v[i]; s2 = fmaf(v[i], v[i], s2); }
    s1 = wsum_f(s1); s2 = wsum_f(s2);
    const float mu = s1 * (1.0f / 2048.0f);
    const float sg = sqrtf(fmaxf(s2 * (1.0f / 2048.0f) - mu * mu, 0.0f));

    // ---- phase 1b: find th with count(v>=th) in [32,56]
    float th  = mu + 2.024f * sg;          // targets E[count]~44
    float blo = mu, bhi = mu + 8.0f * sg;  // brackets
    float thOK = mu; int cOK = 0x7fffffff;
    bool found = false;
#pragma unroll 1
    for (int it = 0; it < 16; ++it) {
        int c = 0;
#pragma unroll
        for (int i = 0; i < 32; ++i) c += __popcll(__ballot(v[i] >= th));
        if (c >= 32 && c < cOK) { cOK = c; thOK = th; }
        if (c >= 32 && c <= 56) { found = true; break; }
        if (c < 32) bhi = th; else blo = th;
        // Gaussian-tail secant step in z-space: d(ln c)/dz ~ -z
        float z  = (th - mu) / fmaxf(sg, 1e-20f);
        float dz = (__logf((float)(c > 0 ? c : 1)) - 3.784f) / fmaxf(z, 0.5f);
        dz = fminf(fmaxf(dz, -0.5f), 0.5f);
        float tn = mu + (z + dz) * sg;
        if (!(tn > blo && tn < bhi)) tn = 0.5f * (blo + bhi);
        th = tn;
    }
    if (!found) th = (cOK != 0x7fffffff) ? thOK : mu;

    // ---- phase 2: compact candidates into LDS (one per lane afterwards)
    unsigned msk = 0;
#pragma unroll
    for (int i = 0; i < 32; ++i) msk |= (v[i] >= th) ? (1u << i) : 0u;
    const int kc   = __popc(msk);
    const int base = wscan_excl(kc, lane);
    int C = __shfl(base + kc, 63);          // total candidates (pre-cap)
    {
        int r = base;
#pragma unroll
        for (int i = 0; i < 32; ++i)
            if (msk & (1u << i)) {
                if (r < 64) { cidxS[wave][r] = lane * 32 + i; cvalS[wave][r] = v[i]; }
                ++r;
            }
    }
    if (C > 64) C = 64;
    __threadfence_block();
    bool  act  = lane < C;
    float aval = cvalS[wave][act ? lane : 0];
    int   acid = cidxS[wave][act ? lane : 0];

    // ---- phase 3: radix-select exact 32nd-largest approx among candidates
    unsigned uu = 0;
    if (act) {
        unsigned t = __float_as_uint(aval);
        uu = t ^ (unsigned)(((int)t >> 31) | 0x80000000);   // order-preserving map
    }
    unsigned T = 0;
#pragma unroll 1
    for (int b = 31; b >= 0; --b) {
        unsigned T2 = T | (1u << b);
        if (__popcll(__ballot(uu >= T2)) >= 32) T = T2;
    }
    const unsigned tfb = (T & 0x80000000u) ? (T ^ 0x80000000u) : ~T;
    const float thf  = __uint_as_float(tfb);
    const float thi2 = thf + 2.0f * TOPK_E;
    const float tlo2 = thf - 2.0f * TOPK_E;

    // ---- phase 3b (rare): band not fully covered by candidates -> append
    if (th > tlo2) {
        unsigned em = 0;
#pragma unroll
        for (int i = 0; i < 32; ++i) em |= (v[i] >= tlo2 && v[i] < th) ? (1u << i) : 0u;
        const int ke = __popc(em);
        const int eb = C + wscan_excl(ke, lane);
        int r = eb;
#pragma unroll
        for (int i = 0; i < 32; ++i)
            if (em & (1u << i)) {
                if (r < 64) { cidxS[wave][r] = lane * 32 + i; cvalS[wave][r] = v[i]; }
                ++r;
            }
        const int etot = __shfl(eb + ke, 63) - C;
        C = C + etot; if (C > 64) C = 64;
        __threadfence_block();
        act  = lane < C;
        aval = cvalS[wave][act ? lane : 0];
        acid = cidxS[wave][act ? lane : 0];
    }

    // ---- phase 4: sure set (owner-side), n_sure, and sure outputs
    unsigned sel = 0;
#pragma unroll
    for (int i = 0; i < 32; ++i) sel |= (v[i] > thi2) ? (1u << i) : 0u;
    int nsure = wsum_i(__popc(sel));
    if (nsure > 32) nsure = 32;                 // pathological-tie safety
    const int slots = 32 - nsure;

    {
        int r = wscan_excl(__popc(sel), lane);
#pragma unroll
        for (int i = 0; i < 32; ++i)
            if (sel & (1u << i)) {
                if (r < 32) {
                    oidx[row * 32 + r] = lane * 32 + i;
                    oval[row * 32 + r] = fmaxf(v[i], 0.0f);
                }
                ++r;
            }
    }

    // ---- phase 5: fp64-exact ranking of the (tiny) band
    const bool bandf = act && (aval >= tlo2) && (aval <= thi2);
    unsigned long long bm = __ballot(bandf);
    int nwin = 0;
    if (slots > 0 && bm) {
        const float* xr = x + (size_t)row * IND + lane * 12;
        const float4v x0 = *(const float4v*)(xr);
        const float4v x1 = *(const float4v*)(xr + 4);
        const float4v x2 = *(const float4v*)(xr + 8);

        double ex = 0.0;
        unsigned long long t = bm;
        while (t) {
            const int l = __builtin_ctzll(t); t &= t - 1;
            const int bidx = __shfl(acid, l);
            const float* wr = Wenc + (size_t)bidx * IND + lane * 12;
            const float4v w0 = *(const float4v*)(wr);
            const float4v w1 = *(const float4v*)(wr + 4);
            const float4v w2 = *(const float4v*)(wr + 8);
            double s = (double)x0.x * (double)w0.x + (double)x0.y * (double)w0.y
                     + (double)x0.z * (double)w0.z + (double)x0.w * (double)w0.w
                     + (double)x1.x * (double)w1.x + (double)x1.y * (double)w1.y
                     + (double)x1.z * (double)w1.z + (double)x1.w * (double)w1.w
                     + (double)x2.x * (double)w2.x + (double)x2.y * (double)w2.y
                     + (double)x2.z * (double)w2.z + (double)x2.w * (double)w2.w;
#pragma unroll
            for (int o = 32; o; o >>= 1) s += __shfl_xor(s, o);
            if (lane == l) ex = s + (double)benc[bidx];
        }

        // rank band members: better := (exact greater) or (equal && smaller idx)
        int rank = 0;
        t = bm;
        while (t) {
            const int l = __builtin_ctzll(t); t &= t - 1;
            const double oex = __shfl(ex, l);
            const int    oid = __shfl(acid, l);
            if (bandf && (oex > ex || (oex == ex && oid < acid))) ++rank;
        }

        unsigned long long wm = __ballot(bandf && rank < slots);
        nwin = __popcll(wm);
        int ss = nsure;
        t = wm;
        while (t) {
            const int l = __builtin_ctzll(t); t &= t - 1;
            const int   widx = __shfl(acid, l);
            const float wv   = __shfl(aval, l);
            if ((widx >> 5) == lane) sel |= 1u << (widx & 31);
            if (lane == 0 && ss < 32) {
                oidx[row * 32 + ss] = widx;
                oval[row * 32 + ss] = fmaxf(wv, 0.0f);
            }
            ++ss;
        }
    }
    // degenerate-row safety: never leave stale workspace slots
    if (lane == 0) {
        int st = nsure + nwin; if (st < 0) st = 0;
        for (int r = st; r < 32; ++r) { oidx[row * 32 + r] = 0; oval[row * 32 + r] = 0.0f; }
    }

    // ---- phase 6: dense h_sparse scatter (vectorized)
    float* hs = hsp + (size_t)row * HID + lane * 32;
#pragma unroll
    for (int ii = 0; ii < 8; ++ii) {
        float4v o;
#pragma unroll
        for (int jj = 0; jj < 4; ++jj) {
            const int i = ii * 4 + jj;
            o[jj] = (sel & (1u << i)) ? fmaxf(v[i], 0.0f) : 0.0f;
        }
        ((float4v*)hs)[ii] = o;
    }
}

// ---------------- sparse decoder: rec = sum val_j * W_decT[idx_j] + b_dec ----
__global__ __launch_bounds__(256) void decode_rows(const int* __restrict__ oidx,
                                                   const float* __restrict__ oval,
                                                   const float* __restrict__ WdT,
                                                   const float* __restrict__ bdec,
                                                   float* __restrict__ rec)
{
    const int lane = threadIdx.x & 63;
    const int wave = threadIdx.x >> 6;
    const int row = blockIdx.x * 4 + wave;
    int   mi = 0; float mv = 0.0f;
    if (lane < 32) { mi = oidx[row * 32 + lane]; mv = oval[row * 32 + lane]; }

    float4v a0 = *(const float4v*)&bdec[lane * 4];
    float4v a1 = *(const float4v*)&bdec[256 + lane * 4];
    float4v a2 = *(const float4v*)&bdec[512 + lane * 4];

    for (int j = 0; j < 32; ++j) {
        const float val = __shfl(mv, j);
        const int   idx = __shfl(mi, j);
        if (val != 0.0f) {                     // wave-uniform branch
            const float* wr = WdT + (size_t)idx * IND;
            a0 += val * *(const float4v*)&wr[lane * 4];
            a1 += val * *(const float4v*)&wr[256 + lane * 4];
            a2 += val * *(const float4v*)&wr[512 + lane * 4];
        }
    }
    float* rp = rec + (size_t)row * IND;
    *(float4v*)&rp[lane * 4] = a0;
    *(float4v*)&rp[256 + lane * 4] = a1;
    *(float4v*)&rp[512 + lane * 4] = a2;
}

extern "C" void kernel_launch(void* const* d_in, const int* in_sizes, int n_in,
                              void* d_out, int out_size, void* d_ws, size_t ws_size,
                              hipStream_t stream)
{
    const float* x    = (const float*)d_in[0];
    const float* Wenc = (const float*)d_in[1];
    const float* benc = (const float*)d_in[2];
    const float* Wdec = (const float*)d_in[3];
    const float* bdec = (const float*)d_in[4];

    float* out  = (float*)d_out;
    float* rec  = out;                                           // 32768*768
    float* hsp  = out + (size_t)BATCH_N * IND;                   // 32768*2048
    float* hpre = out + (size_t)BATCH_N * IND + (size_t)BATCH_N * HID;

    char* ws = (char*)d_ws;
    _Float16* Whi = (_Float16*)ws;                 // 2048*768*2 = 3,145,728 B
    float*    WdT = (float*)(ws + 3145728);        // 6,291,456 B
    int*     tidx = (int*)(ws + 9437184);          // 4,194,304 B
    float*   tval = (float*)(ws + 13631488);       // 4,194,304 B (end ~17 MiB)

    hipLaunchKernelGGL(prep_wenc,   dim3(1536), dim3(256), 0, stream, Wenc, Whi);
    hipLaunchKernelGGL(prep_wdec,   dim3(6144), dim3(256), 0, stream, Wdec, WdT);
    hipLaunchKernelGGL(gemm_enc,    dim3(4096), dim3(256), 0, stream, x, Whi, benc, hpre);
    hipLaunchKernelGGL(topk_refine, dim3(8192), dim3(256), 0, stream, hpre, x, Wenc, benc, hsp, tidx, tval);
    hipLaunchKernelGGL(decode_rows, dim3(8192), dim3(256), 0, stream, tidx, tval, WdT, bdec, rec);
}